// Round 11
// baseline (824.013 us; speedup 1.0000x reference)
//
#include <hip/hip_runtime.h>
#include <hip/hip_bf16.h>

typedef unsigned short u16;
typedef unsigned int u32;
typedef __attribute__((ext_vector_type(8))) short bf16x8;
typedef __attribute__((ext_vector_type(4))) float f32x4;
typedef __attribute__((ext_vector_type(8))) u16 u16x8;
typedef __attribute__((ext_vector_type(4))) u16 u16x4;

#define HIDDEN 2048
#define NBATCH 4
#define QLEN 2048
#define PASTLEN 2048
#define TKV 4096

__device__ __forceinline__ u16 f2b(float f) {
    u32 u = __builtin_bit_cast(u32, f);
    u += 0x7FFFu + ((u >> 16) & 1u);
    return (u16)(u >> 16);
}
__device__ __forceinline__ float b2f(u16 h) {
    u32 u = ((u32)h) << 16;
    return __builtin_bit_cast(float, u);
}

// ------------- all f32->bf16 converts in one dispatch (dst contiguous) ------
__global__ __launch_bounds__(256) void cvt_all(const float* __restrict__ x,
                                               const float* __restrict__ wq,
                                               const float* __restrict__ wk,
                                               const float* __restrict__ wv,
                                               const float* __restrict__ wo,
                                               u16* __restrict__ dst) {
    int i8 = blockIdx.x * 256 + threadIdx.x;        // 0 .. 4194303
    const float* src;
    size_t loc;
    if (i8 < 2097152) {                              // 4 x 524288: Wq Wk Wv Wo
        int w = i8 >> 19;
        loc = (size_t)(i8 & 524287) * 8;
        src = w == 0 ? wq : w == 1 ? wk : w == 2 ? wv : wo;
    } else {                                         // x
        loc = (size_t)(i8 - 2097152) * 8;
        src = x;
    }
    const float4* p = (const float4*)(src + loc);
    float4 a = p[0], b = p[1];
    u16x8 o;
    o[0] = f2b(a.x); o[1] = f2b(a.y); o[2] = f2b(a.z); o[3] = f2b(a.w);
    o[4] = f2b(b.x); o[5] = f2b(b.y); o[6] = f2b(b.z); o[7] = f2b(b.w);
    *(u16x8*)(dst + (size_t)i8 * 8) = o;
}

// --- past_k: copy f32 + bf16; past_v: copy f32 + transposed bf16 (one pass) --
__global__ __launch_bounds__(256) void past_both(const float* __restrict__ pk,
                                                 const float* __restrict__ pv,
                                                 float* __restrict__ outK,
                                                 float* __restrict__ outV,
                                                 u16* __restrict__ kb,
                                                 u16* __restrict__ vt) {
    const int bid = blockIdx.x;
    const int tid = threadIdx.x;
    if (bid < 16384) {                               // K flat copy
        size_t i4 = (size_t)bid * 256 + tid;
        size_t flat = i4 * 4;
        size_t b = flat >> 22;
        size_t rem = flat & 4194303u;
        size_t o = b * ((size_t)TKV * HIDDEN) + rem;
        float4 v = *(const float4*)(pk + flat);
        *(float4*)(outK + o) = v;
        u16x4 w; w[0] = f2b(v.x); w[1] = f2b(v.y); w[2] = f2b(v.z); w[3] = f2b(v.w);
        *(u16x4*)(kb + o) = w;
        return;
    }
    // V: 64x64 tile -> f32 copy (same layout) + bf16 transpose into vt
    const int vb = bid - 16384;                      // 0..4095
    const int b = vb >> 10;
    const int t = vb & 1023;
    const int k0 = (t >> 5) * 64;                    // past row block [0,2048)
    const int d0 = (t & 31) * 64;                    // col block      [0,2048)
    const float* Vb = pv + (size_t)b * PASTLEN * HIDDEN;
    float* Ob = outV + (size_t)b * TKV * HIDDEN;
    u16* Tb = vt + (size_t)b * HIDDEN * TKV;
    __shared__ u16 tt[64][66];
#pragma unroll
    for (int r = 0; r < 4; ++r) {
        int i = r * 256 + tid;
        int kr = i >> 4;
        int dc = (i & 15) * 4;
        float4 v = *(const float4*)&Vb[(size_t)(k0 + kr) * HIDDEN + d0 + dc];
        *(float4*)&Ob[(size_t)(k0 + kr) * HIDDEN + d0 + dc] = v;
        tt[dc + 0][kr] = f2b(v.x);
        tt[dc + 1][kr] = f2b(v.y);
        tt[dc + 2][kr] = f2b(v.z);
        tt[dc + 3][kr] = f2b(v.w);
    }
    __syncthreads();
#pragma unroll
    for (int r = 0; r < 2; ++r) {
        int i = r * 256 + tid;
        int dr = i >> 3;
        int kc = (i & 7) * 8;
        u16x8 w;
#pragma unroll
        for (int j = 0; j < 8; ++j) w[j] = tt[dr][kc + j];
        *(u16x8*)&Tb[(size_t)(d0 + dr) * TKV + k0 + kc] = w;
    }
}

// ------------------- row softmax (bf16 S), causal, -> P bf16 ----------------
__global__ __launch_bounds__(256) void softmax_rows(const u16* __restrict__ S,
                                                    u16* __restrict__ P) {
    const int q = blockIdx.x;
    const int b = blockIdx.y;
    const size_t roff = ((size_t)b * QLEN + q) * (size_t)TKV;
    const int L = q + (TKV - QLEN + 1);
    const int tid = threadIdx.x;
    __shared__ float buf[TKV];
    __shared__ float red[8];
    float mx = -1e30f;
    const u16* Sr = S + roff;
#pragma unroll
    for (int it = 0; it < TKV / 2048; ++it) {
        int i = it * 2048 + tid * 8;
        u16x8 v = *(const u16x8*)&Sr[i];
#pragma unroll
        for (int j = 0; j < 8; ++j) {
            float f = (i + j < L) ? b2f(v[j]) : -1e30f;
            buf[i + j] = f;
            mx = fmaxf(mx, f);
        }
    }
#pragma unroll
    for (int o = 32; o > 0; o >>= 1) mx = fmaxf(mx, __shfl_xor(mx, o));
    if ((tid & 63) == 0) red[tid >> 6] = mx;
    __syncthreads();
    mx = fmaxf(fmaxf(red[0], red[1]), fmaxf(red[2], red[3]));
    float sm = 0.f;
    for (int i = tid; i < TKV; i += 256) {
        float e = __expf(buf[i] - mx);
        buf[i] = e;
        sm += e;
    }
#pragma unroll
    for (int o = 32; o > 0; o >>= 1) sm += __shfl_xor(sm, o);
    if ((tid & 63) == 0) red[4 + (tid >> 6)] = sm;
    __syncthreads();
    float inv = 1.0f / (red[4] + red[5] + red[6] + red[7]);
    u16* Pr = P + roff;
#pragma unroll
    for (int it = 0; it < TKV / 2048; ++it) {
        int i = it * 2048 + tid * 8;
        u16x8 w;
#pragma unroll
        for (int j = 0; j < 8; ++j) w[j] = f2b(buf[i + j] * inv);
        *(u16x8*)&Pr[i] = w;
    }
}

// ------- 128x128 4-wave m97-style double-buffered MFMA K-loop + swizzle ------
// C[m,n]=sum_k A[m,k]*B[n,k]. BK=32. LDS 2 x {A 8KB | B 8KB} = 32 KB -> with
// acc[4][4] (64 AGPR) + ~100 VGPR this runs ~3 blocks/CU: cross-block TLP
// absorbs the barrier drain (m97/m114). __syncthreads() per tile; compiler
// inserts the waitcnts (m97-verified). Swizzle: 16B-slot ^= (row>>1)&3 on
// read, same involution pre-applied to global source (0 conflicts, r4-r10).
__device__ __forceinline__ void kloop128(const u16* __restrict__ Ab, const u16* __restrict__ Bb,
                                         int K, int NT, u16* lds, f32x4 (&acc)[4][4]) {
    const int tid = threadIdx.x;                     // 0..255
    const int wid = tid >> 6, lane = tid & 63;
    const int wr = wid >> 1, wc = wid & 1;           // 2x2 wave grid
    const int lrow = lane & 15, kg = lane >> 4;

    // staging: per 8KB half (512 x 16B chunks), thread t owns chunks t, t+256
    const int c0 = tid, c1 = tid + 256;
    const int r0 = c0 >> 2, r1 = c1 >> 2;            // row 0..127
    const int s0 = (c0 & 3) ^ ((r0 >> 1) & 3);       // swizzled source slot
    const int s1 = (c1 & 3) ^ ((r1 >> 1) & 3);
    const u16* sA0 = Ab + (size_t)r0 * K + s0 * 8;
    const u16* sA1 = Ab + (size_t)r1 * K + s1 * 8;
    const u16* sB0 = Bb + (size_t)r0 * K + s0 * 8;
    const u16* sB1 = Bb + (size_t)r1 * K + s1 * 8;
    const int dd0 = c0 * 8, dd1 = c1 * 8;            // u16 offsets in half

#define STG(t) do { u16* _s = lds + (((t) & 1) << 13);                                   \
    __builtin_amdgcn_global_load_lds((const __attribute__((address_space(1))) void*)(sA0 + (t) * 32), \
        (__attribute__((address_space(3))) void*)(_s + dd0), 16, 0, 0);                  \
    __builtin_amdgcn_global_load_lds((const __attribute__((address_space(1))) void*)(sA1 + (t) * 32), \
        (__attribute__((address_space(3))) void*)(_s + dd1), 16, 0, 0);                  \
    __builtin_amdgcn_global_load_lds((const __attribute__((address_space(1))) void*)(sB0 + (t) * 32), \
        (__attribute__((address_space(3))) void*)(_s + 4096 + dd0), 16, 0, 0);           \
    __builtin_amdgcn_global_load_lds((const __attribute__((address_space(1))) void*)(sB1 + (t) * 32), \
        (__attribute__((address_space(3))) void*)(_s + 4096 + dd1), 16, 0, 0); } while (0)

    // frag offsets (u16): physical slot = kg ^ ((lrow>>1)&3); frag stride 16 rows
    const int kx = (kg ^ ((lrow >> 1) & 3)) * 8;
    const int aBase = (wr * 64 + lrow) * 32 + kx;
    const int bBase = 4096 + (wc * 64 + lrow) * 32 + kx;

    STG(0);
    for (int t = 0; t < NT; ++t) {
        __syncthreads();                             // drains vmcnt: buf(t) staged
        if (t + 1 < NT) STG(t + 1);
        const u16* base = lds + ((t & 1) << 13);
        bf16x8 af[4], bf[4];
#pragma unroll
        for (int i = 0; i < 4; ++i) af[i] = *(const bf16x8*)&base[aBase + i * 512];
#pragma unroll
        for (int j = 0; j < 4; ++j) bf[j] = *(const bf16x8*)&base[bBase + j * 512];
#pragma unroll
        for (int i = 0; i < 4; ++i)
#pragma unroll
            for (int j = 0; j < 4; ++j)
                acc[i][j] = __builtin_amdgcn_mfma_f32_16x16x32_bf16(af[i], bf[j], acc[i][j], 0, 0, 0);
    }
#undef STG
}

// ------------------ fused QKV projection GEMM (N = 6144 concat) -------------
__global__ __launch_bounds__(256, 3)
void qkv_gemm(const u16* __restrict__ xb, const u16* __restrict__ wcat,
              const float* __restrict__ bq, const float* __restrict__ bk,
              const float* __restrict__ bv,
              u16* __restrict__ qb, float* __restrict__ outK, u16* __restrict__ kb,
              float* __restrict__ outV, u16* __restrict__ vt) {
    __shared__ u16 lds[16384];                       // 32 KB
    const int nwg = gridDim.x * gridDim.y;           // 64*48 = 3072
    const int l = blockIdx.x + gridDim.x * blockIdx.y;   // HW dispatch-linear
    const int swzid = (l & 7) * (nwg >> 3) + (l >> 3);   // XCD chunks, n fastest
    const int m0 = (swzid / gridDim.y) * 128;        // [0, 8192)
    const int n0 = (swzid % gridDim.y) * 128;        // [0, 6144)
    f32x4 acc[4][4] = {};
    kloop128(xb + (size_t)m0 * HIDDEN, wcat + (size_t)n0 * HIDDEN, HIDDEN, HIDDEN / 32, lds, acc);

    const int tid = threadIdx.x;
    const int wid = tid >> 6, lane = tid & 63;
    const int wr = wid >> 1, wc = wid & 1;
    const int lrow = lane & 15, kg = lane >> 4;
    const int w = n0 >> 11;                          // 0=Q 1=K 2=V (block-uniform)
    const int nn0 = n0 & 2047;
    const float* bias = w == 0 ? bq : w == 1 ? bk : bv;
    const int bb = m0 >> 11;                         // batch
#pragma unroll
    for (int i = 0; i < 4; ++i) {
#pragma unroll
        for (int j = 0; j < 4; ++j) {
            const int n = nn0 + wc * 64 + j * 16 + lrow;
            const int mB = m0 + wr * 64 + i * 16 + kg * 4;
            const int tokB = mB & (QLEN - 1);
            float vv[4];
#pragma unroll
            for (int r = 0; r < 4; ++r) vv[r] = acc[i][j][r] + bias[n];
            if (w == 0) {
#pragma unroll
                for (int r = 0; r < 4; ++r)
                    qb[(size_t)(mB + r) * HIDDEN + n] = f2b(vv[r]);
            } else if (w == 1) {
#pragma unroll
                for (int r = 0; r < 4; ++r) {
                    size_t crow = (size_t)bb * TKV + PASTLEN + tokB + r;
                    outK[crow * HIDDEN + n] = vv[r];
                    kb[crow * HIDDEN + n] = f2b(vv[r]);
                }
            } else {
#pragma unroll
                for (int r = 0; r < 4; ++r) {
                    size_t crow = (size_t)bb * TKV + PASTLEN + tokB + r;
                    outV[crow * HIDDEN + n] = vv[r];
                }
                u16x4 wv4;
#pragma unroll
                for (int r = 0; r < 4; ++r) wv4[r] = f2b(vv[r]);
                *(u16x4*)&vt[(size_t)bb * ((size_t)HIDDEN * TKV) +
                             (size_t)n * TKV + PASTLEN + tokB] = wv4;
            }
        }
    }
}

// -------------------- generic 128x128 GEMM (scores/PV/outproj) --------------
template<bool WF32, bool WB16, bool BIAS, bool SCALE, bool SKIPDEAD, bool TRIM, bool SWAPXY>
__global__ __launch_bounds__(256, 3)
void gemm128(const u16* __restrict__ A, size_t aBatch,
             const u16* __restrict__ Bp, size_t bBatch,
             const float* __restrict__ bias,
             float* __restrict__ Cf, int cfLd,
             u16* __restrict__ Cb, size_t cbBatch, int cbLd,
             int K, float scale) {
    __shared__ u16 lds[16384];
    const int nwg = gridDim.x * gridDim.y;
    const int l = blockIdx.x + gridDim.x * blockIdx.y;   // HW dispatch-linear
    const int swzid = (l & 7) * (nwg >> 3) + (l >> 3);
    const int t0 = swzid / gridDim.y, t1 = swzid % gridDim.y;
    const int m0 = (SWAPXY ? t1 : t0) * 128;
    const int n0 = (SWAPXY ? t0 : t1) * 128;
    if (SKIPDEAD && n0 >= m0 + 128 + PASTLEN) return;    // before any barrier
    const int bz = blockIdx.z;

    int NT = K / 32;
    if (TRIM) { int tmax = (m0 + 128 + PASTLEN) / 32; NT = tmax < NT ? tmax : NT; }

    f32x4 acc[4][4] = {};
    kloop128(A + (size_t)bz * aBatch + (size_t)m0 * K,
             Bp + (size_t)bz * bBatch + (size_t)n0 * K, K, NT, lds, acc);

    const int tid = threadIdx.x;
    const int wid = tid >> 6, lane = tid & 63;
    const int wr = wid >> 1, wc = wid & 1;
    const int lrow = lane & 15, kg = lane >> 4;
    float* Cfb = WF32 ? Cf : nullptr;
    u16* Cbb = WB16 ? Cb + (size_t)bz * cbBatch : nullptr;
#pragma unroll
    for (int i = 0; i < 4; ++i) {
#pragma unroll
        for (int j = 0; j < 4; ++j) {
            const int n = n0 + wc * 64 + j * 16 + lrow;
            const int mB = m0 + wr * 64 + i * 16 + kg * 4;
#pragma unroll
            for (int r = 0; r < 4; ++r) {
                float v = acc[i][j][r];
                if (SCALE) v *= scale;
                if (BIAS) v += bias[n];
                if (WF32) Cfb[(size_t)(mB + r) * cfLd + n] = v;
                if (WB16) Cbb[(size_t)(mB + r) * cbLd + n] = f2b(v);
            }
        }
    }
}

// --------------------------------- launcher ---------------------------------
extern "C" void kernel_launch(void* const* d_in, const int* in_sizes, int n_in,
                              void* d_out, int out_size, void* d_ws, size_t ws_size,
                              hipStream_t stream) {
    (void)in_sizes; (void)n_in; (void)out_size; (void)ws_size;
    const float* x  = (const float*)d_in[0];
    const float* pk = (const float*)d_in[1];
    const float* pv = (const float*)d_in[2];
    const float* Wq = (const float*)d_in[3];
    const float* bq = (const float*)d_in[4];
    const float* Wk = (const float*)d_in[5];
    const float* bk = (const float*)d_in[6];
    const float* Wv = (const float*)d_in[7];
    const float* bv = (const float*)d_in[8];
    const float* Wo = (const float*)d_in[9];
    const float* bo = (const float*)d_in[10];

    float* out  = (float*)d_out;
    float* outK = out + (size_t)NBATCH * QLEN * HIDDEN;
    float* outV = outK + (size_t)NBATCH * TKV * HIDDEN;

    char* ws = (char*)d_ws;
    u16* wqb = (u16*)ws;                      // [Wq|Wk|Wv|Wo] bf16, contiguous
    u16* wob = wqb + 3 * 4194304;
    u16* xb  = wqb + 4 * 4194304;             // x bf16 [8192,2048]
    u16* qb  = xb + 16777216;                 // Q bf16; later ctx bf16
    u16* kb  = qb + 16777216;                 // K bf16 [B,4096,2048]; later P
    u16* vt  = kb + 33554432;                 // V^T bf16 [B,2048,4096]
    u16* sbuf = vt + 33554432;                // S bf16 [B,2048,4096]

    dim3 blk(256);

    cvt_all<<<16384, blk, 0, stream>>>(x, Wq, Wk, Wv, Wo, wqb);
    past_both<<<20480, blk, 0, stream>>>(pk, pv, outK, outV, kb, vt);

    // fused QKV projections: M=8192, N=6144, K=2048 -> 64x48 tiles of 128
    qkv_gemm<<<dim3(64, 48, 1), blk, 0, stream>>>(xb, wqb, bq, bk, bv,
                                                  qb, outK, kb, outV, vt);

    // scores: per batch M=2048, N=4096, K=2048 -> S bf16; SWAPXY (m fastest)
    const float scl = 0.022097086912079608f;
    gemm128<false, true, false, true, true, false, true><<<dim3(32, 16, NBATCH), blk, 0, stream>>>(
        qb, 4194304, kb, 8388608, nullptr, nullptr, 0, sbuf, 8388608, TKV, HIDDEN, scl);

    softmax_rows<<<dim3(QLEN, NBATCH), blk, 0, stream>>>(sbuf, kb);

    // PV: per batch M=2048, N=2048, K=4096 (causal-trimmed) -> ctx bf16 in qb
    gemm128<false, true, false, false, false, true, false><<<dim3(16, 16, NBATCH), blk, 0, stream>>>(
        kb, 8388608, vt, 8388608, nullptr, nullptr, 0, qb, 4194304, HIDDEN, TKV, 1.f);

    // output projection: M=8192, N=2048, K=2048 -> d_out f32
    gemm128<true, false, true, false, false, false, false><<<dim3(64, 16, 1), blk, 0, stream>>>(
        qb, 0, wob, 0, bo, out, HIDDEN, nullptr, 0, 0, HIDDEN, 1.f);
}

// Round 12
// 647.284 us; speedup vs baseline: 1.2730x; 1.2730x over previous
//
#include <hip/hip_runtime.h>
#include <hip/hip_bf16.h>

typedef unsigned short u16;
typedef unsigned int u32;
typedef __attribute__((ext_vector_type(8))) short bf16x8;
typedef __attribute__((ext_vector_type(4))) float f32x4;
typedef __attribute__((ext_vector_type(8))) u16 u16x8;
typedef __attribute__((ext_vector_type(4))) u16 u16x4;

#define HIDDEN 2048
#define NBATCH 4
#define QLEN 2048
#define PASTLEN 2048
#define TKV 4096

#define VMCNT(n) asm volatile("s_waitcnt vmcnt(" #n ")" ::: "memory")
#define LGKM0    asm volatile("s_waitcnt lgkmcnt(0)" ::: "memory")
#define BAR      asm volatile("s_barrier" ::: "memory")
#define SCHEDB   __builtin_amdgcn_sched_barrier(0)

__device__ __forceinline__ u16 f2b(float f) {
    u32 u = __builtin_bit_cast(u32, f);
    u += 0x7FFFu + ((u >> 16) & 1u);
    return (u16)(u >> 16);
}
__device__ __forceinline__ float b2f(u16 h) {
    u32 u = ((u32)h) << 16;
    return __builtin_bit_cast(float, u);
}

// ------------- all f32->bf16 converts in one dispatch (dst contiguous) ------
__global__ __launch_bounds__(256) void cvt_all(const float* __restrict__ x,
                                               const float* __restrict__ wq,
                                               const float* __restrict__ wk,
                                               const float* __restrict__ wv,
                                               const float* __restrict__ wo,
                                               u16* __restrict__ dst) {
    int i8 = blockIdx.x * 256 + threadIdx.x;        // 0 .. 4194303
    const float* src;
    size_t loc;
    if (i8 < 2097152) {                              // 4 x 524288: Wq Wk Wv Wo
        int w = i8 >> 19;
        loc = (size_t)(i8 & 524287) * 8;
        src = w == 0 ? wq : w == 1 ? wk : w == 2 ? wv : wo;
    } else {                                         // x
        loc = (size_t)(i8 - 2097152) * 8;
        src = x;
    }
    const float4* p = (const float4*)(src + loc);
    float4 a = p[0], b = p[1];
    u16x8 o;
    o[0] = f2b(a.x); o[1] = f2b(a.y); o[2] = f2b(a.z); o[3] = f2b(a.w);
    o[4] = f2b(b.x); o[5] = f2b(b.y); o[6] = f2b(b.z); o[7] = f2b(b.w);
    *(u16x8*)(dst + (size_t)i8 * 8) = o;
}

// --- past_k: copy f32 + bf16; past_v: copy f32 + transposed bf16 (one pass) --
__global__ __launch_bounds__(256) void past_both(const float* __restrict__ pk,
                                                 const float* __restrict__ pv,
                                                 float* __restrict__ outK,
                                                 float* __restrict__ outV,
                                                 u16* __restrict__ kb,
                                                 u16* __restrict__ vt) {
    const int bid = blockIdx.x;
    const int tid = threadIdx.x;
    if (bid < 16384) {                               // K flat copy
        size_t i4 = (size_t)bid * 256 + tid;
        size_t flat = i4 * 4;
        size_t b = flat >> 22;
        size_t rem = flat & 4194303u;
        size_t o = b * ((size_t)TKV * HIDDEN) + rem;
        float4 v = *(const float4*)(pk + flat);
        *(float4*)(outK + o) = v;
        u16x4 w; w[0] = f2b(v.x); w[1] = f2b(v.y); w[2] = f2b(v.z); w[3] = f2b(v.w);
        *(u16x4*)(kb + o) = w;
        return;
    }
    // V: 64x64 tile -> f32 copy (same layout) + bf16 transpose into vt
    const int vb = bid - 16384;                      // 0..4095
    const int b = vb >> 10;
    const int t = vb & 1023;
    const int k0 = (t >> 5) * 64;                    // past row block [0,2048)
    const int d0 = (t & 31) * 64;                    // col block      [0,2048)
    const float* Vb = pv + (size_t)b * PASTLEN * HIDDEN;
    float* Ob = outV + (size_t)b * TKV * HIDDEN;
    u16* Tb = vt + (size_t)b * HIDDEN * TKV;
    __shared__ u16 tt[64][66];
#pragma unroll
    for (int r = 0; r < 4; ++r) {
        int i = r * 256 + tid;
        int kr = i >> 4;
        int dc = (i & 15) * 4;
        float4 v = *(const float4*)&Vb[(size_t)(k0 + kr) * HIDDEN + d0 + dc];
        *(float4*)&Ob[(size_t)(k0 + kr) * HIDDEN + d0 + dc] = v;
        tt[dc + 0][kr] = f2b(v.x);
        tt[dc + 1][kr] = f2b(v.y);
        tt[dc + 2][kr] = f2b(v.z);
        tt[dc + 3][kr] = f2b(v.w);
    }
    __syncthreads();
#pragma unroll
    for (int r = 0; r < 2; ++r) {
        int i = r * 256 + tid;
        int dr = i >> 3;
        int kc = (i & 7) * 8;
        u16x8 w;
#pragma unroll
        for (int j = 0; j < 8; ++j) w[j] = tt[dr][kc + j];
        *(u16x8*)&Tb[(size_t)(d0 + dr) * TKV + k0 + kc] = w;
    }
}

// ------------------- row softmax (bf16 S), causal, -> P bf16 ----------------
__global__ __launch_bounds__(256) void softmax_rows(const u16* __restrict__ S,
                                                    u16* __restrict__ P) {
    const int q = blockIdx.x;
    const int b = blockIdx.y;
    const size_t roff = ((size_t)b * QLEN + q) * (size_t)TKV;
    const int L = q + (TKV - QLEN + 1);
    const int tid = threadIdx.x;
    __shared__ float buf[TKV];
    __shared__ float red[8];
    float mx = -1e30f;
    const u16* Sr = S + roff;
#pragma unroll
    for (int it = 0; it < TKV / 2048; ++it) {
        int i = it * 2048 + tid * 8;
        u16x8 v = *(const u16x8*)&Sr[i];
#pragma unroll
        for (int j = 0; j < 8; ++j) {
            float f = (i + j < L) ? b2f(v[j]) : -1e30f;
            buf[i + j] = f;
            mx = fmaxf(mx, f);
        }
    }
#pragma unroll
    for (int o = 32; o > 0; o >>= 1) mx = fmaxf(mx, __shfl_xor(mx, o));
    if ((tid & 63) == 0) red[tid >> 6] = mx;
    __syncthreads();
    mx = fmaxf(fmaxf(red[0], red[1]), fmaxf(red[2], red[3]));
    float sm = 0.f;
    for (int i = tid; i < TKV; i += 256) {
        float e = __expf(buf[i] - mx);
        buf[i] = e;
        sm += e;
    }
#pragma unroll
    for (int o = 32; o > 0; o >>= 1) sm += __shfl_xor(sm, o);
    if ((tid & 63) == 0) red[4 + (tid >> 6)] = sm;
    __syncthreads();
    float inv = 1.0f / (red[4] + red[5] + red[6] + red[7]);
    u16* Pr = P + roff;
#pragma unroll
    for (int it = 0; it < TKV / 2048; ++it) {
        int i = it * 2048 + tid * 8;
        u16x8 w;
#pragma unroll
        for (int j = 0; j < 8; ++j) w[j] = f2b(buf[i + j] * inv);
        *(u16x8*)&Pr[i] = w;
    }
}

// ----------- 256x256 BK=64 4-phase counted-vmcnt MFMA K-loop (8 waves) ------
// Round-6 verified best (qkv 230us / MfmaUtil 40%). LDS: 2 slots x 4 quarters
// {AK0,BK0,AK1,BK1}, 16KB each. Per K-tile: 4 phases, each issues ONE quarter
// of tile t+1 and runs 16 MFMA behind an LGKM0 gate; vmcnt(4)+BAR twice per
// tile (mid: K1 of t landed; end: AK0/BK0 of t+1 landed) - never drains.
// Swizzle: 16B-slot ^= (row>>1)&3 on read, same involution pre-applied to the
// global source (0 bank conflicts, verified r4-r11).
__device__ __forceinline__ void kloop64(const u16* __restrict__ Ab, const u16* __restrict__ Bb,
                                        int K, int NT, u16* lds, f32x4 (&acc)[8][4]) {
    const int tid = threadIdx.x;
    const int wid = tid >> 6, lane = tid & 63;
    const int wr = wid >> 2, wc = wid & 3;
    const int lrow = lane & 15, kg = lane >> 4;

    const int db0 = tid << 4, db1 = (tid + 512) << 4;
    const int r0 = db0 >> 6, r1 = db1 >> 6;
    const int ls0 = ((db0 >> 4) & 3) ^ ((r0 >> 1) & 3);
    const int ls1 = ((db1 >> 4) & 3) ^ ((r1 >> 1) & 3);
    const u16* sA0 = Ab + (size_t)r0 * K + ls0 * 8;
    const u16* sA1 = Ab + (size_t)r1 * K + ls1 * 8;
    const u16* sB0 = Bb + (size_t)r0 * K + ls0 * 8;
    const u16* sB1 = Bb + (size_t)r1 * K + ls1 * 8;
    const int dd0 = db0 >> 1, dd1 = db1 >> 1;       // u16 offsets in quarter

#define ISSUE_Q(p0, p1, koff, dstbase) do {                                              \
    __builtin_amdgcn_global_load_lds((const __attribute__((address_space(1))) void*)((p0) + (koff)), \
        (__attribute__((address_space(3))) void*)((dstbase) + dd0), 16, 0, 0);           \
    __builtin_amdgcn_global_load_lds((const __attribute__((address_space(1))) void*)((p1) + (koff)), \
        (__attribute__((address_space(3))) void*)((dstbase) + dd1), 16, 0, 0); } while (0)
#define IAK0(t) ISSUE_Q(sA0, sA1, (t) * 64,      lds + (((t) & 1) << 15) + 0)
#define IBK0(t) ISSUE_Q(sB0, sB1, (t) * 64,      lds + (((t) & 1) << 15) + 8192)
#define IAK1(t) ISSUE_Q(sA0, sA1, (t) * 64 + 32, lds + (((t) & 1) << 15) + 16384)
#define IBK1(t) ISSUE_Q(sB0, sB1, (t) * 64 + 32, lds + (((t) & 1) << 15) + 24576)

    // prologue: whole tile 0; wait first two quarters (AK0,BK0)
    IAK0(0); IBK0(0); IAK1(0); IBK1(0);
    VMCNT(4);
    BAR;

    const int kx = (kg ^ ((lrow >> 1) & 3)) * 8;
    const int aBase = (wr * 128 + lrow) * 32 + kx;
    const int bBase = (wc * 64 + lrow) * 32 + kx;

    for (int t = 0; t < NT; ++t) {
        u16* base = lds + ((t & 1) << 15);
        const u16* qA0 = base;
        const u16* qB0 = base + 8192;
        const u16* qA1 = base + 16384;
        const u16* qB1 = base + 24576;
        const bool pf = (t + 1 < NT);
        bf16x8 af[4], bf[4];
        // ---- P1: k-step 0, rows lo ----
        if (pf) IAK0(t + 1);
#pragma unroll
        for (int i = 0; i < 4; ++i) af[i] = *(const bf16x8*)&qA0[aBase + i * 512];
#pragma unroll
        for (int j = 0; j < 4; ++j) bf[j] = *(const bf16x8*)&qB0[bBase + j * 512];
        LGKM0; SCHEDB;
        __builtin_amdgcn_s_setprio(1);
#pragma unroll
        for (int i = 0; i < 4; ++i)
#pragma unroll
            for (int j = 0; j < 4; ++j)
                acc[i][j] = __builtin_amdgcn_mfma_f32_16x16x32_bf16(af[i], bf[j], acc[i][j], 0, 0, 0);
        __builtin_amdgcn_s_setprio(0);
        // ---- P2: k-step 0, rows hi ----
        if (pf) IBK0(t + 1);
#pragma unroll
        for (int i = 0; i < 4; ++i) af[i] = *(const bf16x8*)&qA0[aBase + (4 + i) * 512];
        LGKM0; SCHEDB;
        __builtin_amdgcn_s_setprio(1);
#pragma unroll
        for (int i = 0; i < 4; ++i)
#pragma unroll
            for (int j = 0; j < 4; ++j)
                acc[4 + i][j] = __builtin_amdgcn_mfma_f32_16x16x32_bf16(af[i], bf[j], acc[4 + i][j], 0, 0, 0);
        __builtin_amdgcn_s_setprio(0);
        // mid guard: K1 quarters of tile t landed (next AK0/BK0 may be in flight)
        if (pf) { VMCNT(4); } else { VMCNT(0); }
        BAR;
        // ---- P3: k-step 1, rows lo ----
        if (pf) IAK1(t + 1);
#pragma unroll
        for (int i = 0; i < 4; ++i) af[i] = *(const bf16x8*)&qA1[aBase + i * 512];
#pragma unroll
        for (int j = 0; j < 4; ++j) bf[j] = *(const bf16x8*)&qB1[bBase + j * 512];
        LGKM0; SCHEDB;
        __builtin_amdgcn_s_setprio(1);
#pragma unroll
        for (int i = 0; i < 4; ++i)
#pragma unroll
            for (int j = 0; j < 4; ++j)
                acc[i][j] = __builtin_amdgcn_mfma_f32_16x16x32_bf16(af[i], bf[j], acc[i][j], 0, 0, 0);
        __builtin_amdgcn_s_setprio(0);
        // ---- P4: k-step 1, rows hi ----
        if (pf) IBK1(t + 1);
#pragma unroll
        for (int i = 0; i < 4; ++i) af[i] = *(const bf16x8*)&qA1[aBase + (4 + i) * 512];
        LGKM0; SCHEDB;
        __builtin_amdgcn_s_setprio(1);
#pragma unroll
        for (int i = 0; i < 4; ++i)
#pragma unroll
            for (int j = 0; j < 4; ++j)
                acc[4 + i][j] = __builtin_amdgcn_mfma_f32_16x16x32_bf16(af[i], bf[j], acc[4 + i][j], 0, 0, 0);
        __builtin_amdgcn_s_setprio(0);
        // tile boundary: AK0/BK0 of tile t+1 landed (K1 quarters in flight)
        if (pf) { VMCNT(4); BAR; }
    }
#undef ISSUE_Q
#undef IAK0
#undef IBK0
#undef IAK1
#undef IBK1
}

// ------------------ fused QKV projection GEMM (N = 6144 concat) -------------
__global__ __launch_bounds__(512, 2)
void qkv_gemm(const u16* __restrict__ xb, const u16* __restrict__ wcat,
              const float* __restrict__ bq, const float* __restrict__ bk,
              const float* __restrict__ bv,
              u16* __restrict__ qb, float* __restrict__ outK, u16* __restrict__ kb,
              float* __restrict__ outV, u16* __restrict__ vt) {
    __shared__ u16 lds[65536];
    const int nwg = gridDim.x * gridDim.y;                 // 768
    const int l = blockIdx.x + gridDim.x * blockIdx.y;     // HW dispatch-linear
    const int swzid = (l & 7) * (nwg >> 3) + (l >> 3);     // XCD chunks, n fastest
    const int m0 = (swzid / gridDim.y) * 256;              // [0, 8192)
    const int n0 = (swzid % gridDim.y) * 256;              // [0, 6144)
    f32x4 acc[8][4] = {};
    kloop64(xb + (size_t)m0 * HIDDEN, wcat + (size_t)n0 * HIDDEN, HIDDEN, HIDDEN / 64, lds, acc);

    const int tid = threadIdx.x;
    const int wid = tid >> 6, lane = tid & 63;
    const int wr = wid >> 2, wc = wid & 3;
    const int lrow = lane & 15, kg = lane >> 4;
    const int w = n0 >> 11;                                // 0=Q 1=K 2=V
    const int nn0 = n0 & 2047;
    const float* bias = w == 0 ? bq : w == 1 ? bk : bv;
    const int bb = m0 >> 11;                               // batch
#pragma unroll
    for (int i = 0; i < 8; ++i) {
#pragma unroll
        for (int j = 0; j < 4; ++j) {
            const int n = nn0 + wc * 64 + j * 16 + lrow;
            const int mB = m0 + wr * 128 + i * 16 + kg * 4;
            const int tokB = mB & (QLEN - 1);
            float vv[4];
#pragma unroll
            for (int r = 0; r < 4; ++r) vv[r] = acc[i][j][r] + bias[n];
            if (w == 0) {
#pragma unroll
                for (int r = 0; r < 4; ++r)
                    qb[(size_t)(mB + r) * HIDDEN + n] = f2b(vv[r]);
            } else if (w == 1) {
#pragma unroll
                for (int r = 0; r < 4; ++r) {
                    size_t crow = (size_t)bb * TKV + PASTLEN + tokB + r;
                    outK[crow * HIDDEN + n] = vv[r];
                    kb[crow * HIDDEN + n] = f2b(vv[r]);
                }
            } else {
#pragma unroll
                for (int r = 0; r < 4; ++r) {
                    size_t crow = (size_t)bb * TKV + PASTLEN + tokB + r;
                    outV[crow * HIDDEN + n] = vv[r];
                }
                u16x4 wv4;
#pragma unroll
                for (int r = 0; r < 4; ++r) wv4[r] = f2b(vv[r]);
                *(u16x4*)&vt[(size_t)bb * ((size_t)HIDDEN * TKV) +
                             (size_t)n * TKV + PASTLEN + tokB] = wv4;
            }
        }
    }
}

// -------------------- generic 256x256 GEMM (scores/PV/outproj) --------------
template<bool WF32, bool WB16, bool BIAS, bool SCALE, bool SKIPDEAD, bool TRIM, bool SWAPXY>
__global__ __launch_bounds__(512, 2)
void gemm256(const u16* __restrict__ A, size_t aBatch,
             const u16* __restrict__ Bp, size_t bBatch,
             const float* __restrict__ bias,
             float* __restrict__ Cf, int cfLd,
             u16* __restrict__ Cb, size_t cbBatch, int cbLd,
             int K, float scale) {
    __shared__ u16 lds[65536];
    const int nwg = gridDim.x * gridDim.y;
    const int l = blockIdx.x + gridDim.x * blockIdx.y;     // HW dispatch-linear
    const int swzid = (l & 7) * (nwg >> 3) + (l >> 3);
    const int t0 = swzid / gridDim.y, t1 = swzid % gridDim.y;
    const int m0 = (SWAPXY ? t1 : t0) * 256;
    const int n0 = (SWAPXY ? t0 : t1) * 256;
    if (SKIPDEAD && n0 >= m0 + 256 + PASTLEN) return;
    const int bz = blockIdx.z;

    int NT = K / 64;
    if (TRIM) { int tmax = (m0 + 256 + PASTLEN) / 64; NT = tmax < NT ? tmax : NT; }

    f32x4 acc[8][4] = {};
    kloop64(A + (size_t)bz * aBatch + (size_t)m0 * K,
            Bp + (size_t)bz * bBatch + (size_t)n0 * K, K, NT, lds, acc);

    const int tid = threadIdx.x;
    const int wid = tid >> 6, lane = tid & 63;
    const int wr = wid >> 2, wc = wid & 3;
    const int lrow = lane & 15, kg = lane >> 4;
    float* Cfb = WF32 ? Cf : nullptr;
    u16* Cbb = WB16 ? Cb + (size_t)bz * cbBatch : nullptr;
#pragma unroll
    for (int i = 0; i < 8; ++i) {
#pragma unroll
        for (int j = 0; j < 4; ++j) {
            const int n = n0 + wc * 64 + j * 16 + lrow;
            const int mB = m0 + wr * 128 + i * 16 + kg * 4;
#pragma unroll
            for (int r = 0; r < 4; ++r) {
                float v = acc[i][j][r];
                if (SCALE) v *= scale;
                if (BIAS) v += bias[n];
                if (WF32) Cfb[(size_t)(mB + r) * cfLd + n] = v;
                if (WB16) Cbb[(size_t)(mB + r) * cbLd + n] = f2b(v);
            }
        }
    }
}

// --------------------------------- launcher ---------------------------------
extern "C" void kernel_launch(void* const* d_in, const int* in_sizes, int n_in,
                              void* d_out, int out_size, void* d_ws, size_t ws_size,
                              hipStream_t stream) {
    (void)in_sizes; (void)n_in; (void)out_size; (void)ws_size;
    const float* x  = (const float*)d_in[0];
    const float* pk = (const float*)d_in[1];
    const float* pv = (const float*)d_in[2];
    const float* Wq = (const float*)d_in[3];
    const float* bq = (const float*)d_in[4];
    const float* Wk = (const float*)d_in[5];
    const float* bk = (const float*)d_in[6];
    const float* Wv = (const float*)d_in[7];
    const float* bv = (const float*)d_in[8];
    const float* Wo = (const float*)d_in[9];
    const float* bo = (const float*)d_in[10];

    float* out  = (float*)d_out;
    float* outK = out + (size_t)NBATCH * QLEN * HIDDEN;
    float* outV = outK + (size_t)NBATCH * TKV * HIDDEN;

    char* ws = (char*)d_ws;
    u16* wqb = (u16*)ws;                      // [Wq|Wk|Wv|Wo] bf16, contiguous
    u16* wob = wqb + 3 * 4194304;
    u16* xb  = wqb + 4 * 4194304;             // x bf16 [8192,2048]
    u16* qb  = xb + 16777216;                 // Q bf16; later ctx bf16
    u16* kb  = qb + 16777216;                 // K bf16 [B,4096,2048]; later P
    u16* vt  = kb + 33554432;                 // V^T bf16 [B,2048,4096]
    u16* sbuf = vt + 33554432;                // S bf16 [B,2048,4096]

    dim3 blk(256);
    dim3 gblk(512);

    cvt_all<<<16384, blk, 0, stream>>>(x, Wq, Wk, Wv, Wo, wqb);
    past_both<<<20480, blk, 0, stream>>>(pk, pv, outK, outV, kb, vt);

    // fused QKV projections: M=8192, N=6144, K=2048
    qkv_gemm<<<dim3(32, 24, 1), gblk, 0, stream>>>(xb, wqb, bq, bk, bv,
                                                   qb, outK, kb, outV, vt);

    // scores: per batch M=2048, N=4096, K=2048 -> S bf16; SWAPXY chunking
    const float scl = 0.022097086912079608f;
    gemm256<false, true, false, true, true, false, true><<<dim3(16, 8, NBATCH), gblk, 0, stream>>>(
        qb, 4194304, kb, 8388608, nullptr, nullptr, 0, sbuf, 8388608, TKV, HIDDEN, scl);

    softmax_rows<<<dim3(QLEN, NBATCH), blk, 0, stream>>>(sbuf, kb);

    // PV: per batch M=2048, N=2048, K=4096 (causal-trimmed) -> ctx bf16 in qb
    gemm256<false, true, false, false, false, true, false><<<dim3(8, 8, NBATCH), gblk, 0, stream>>>(
        kb, 8388608, vt, 8388608, nullptr, nullptr, 0, qb, 4194304, HIDDEN, TKV, 1.f);

    // output projection: M=8192, N=2048, K=2048 -> d_out f32
    gemm256<true, false, true, false, false, false, false><<<dim3(32, 8, 1), gblk, 0, stream>>>(
        qb, 0, wob, 0, bo, out, HIDDEN, nullptr, 0, 0, HIDDEN, 1.f);
}